// Round 4
// baseline (504.364 us; speedup 1.0000x reference)
//
#include <hip/hip_runtime.h>

// GroupSparseActivation: x (32,2048,1024) fp32.
// v4 = v1 topology (512 blocks x 512 thr — best measured) + two fixes aimed
// at the BW ceiling (all variants tie ~183 us @ 2.3 TB/s while fillBuffer
// hits 6.6 TB/s in the same graph):
//  (1) XCD swizzle of (b,g): default blockIdx=b*16+g round-robins 8 XCDs so
//      XCD i only hosts g in {i,i+8} -> all its HBM traffic has addr bits
//      [8:12) pinned to 2/16 values (256B column stripes, 4KiB stride).
//      New map: g=(n>>3)&15, b=((n>>7)<<3)|(n&7) (bijective) -> each XCD
//      sees all 16 column offsets.
//  (2) Phase A 4-deep: 4 batched loads, then 4 INTERLEAVED butterfly chains
//      (per-row tree unchanged: double dot, xor 1,2,4,8 -> bit-identical
//      norms => absmax stays 0). __launch_bounds__(512,4) (VGPR cap 128,
//      v3 compiled to 32) lets the compiler hoist the next quad of loads
//      under the ~400-cycle chains => >=8KiB in flight per wave.
// Phase B: v3's verified u32-lexicographic 42-bit bisection (bit-exact vs
// the u64 composite-key radix select). Phase C: v1's verified loop.

#define BB 32
#define SS 2048
#define GG 16
#define KTOP 256

__device__ inline double shfl_xor_dbl(double v, int m) {
  union {
    double d;
    int i[2];
  } u;
  u.d = v;
  u.i[0] = __shfl_xor(u.i[0], m, 64);
  u.i[1] = __shfl_xor(u.i[1], m, 64);
  return u.d;
}

__global__ __launch_bounds__(512, 4) void gsa_v4(const float4* __restrict__ x4,
                                                 float4* __restrict__ out4) {
  __shared__ float norm[SS];       // 8 KiB
  __shared__ unsigned int Tch_sh;  // threshold: norm-bits part
  __shared__ int Tscl_sh;          // threshold: max selected s at ==ch
  const int t = threadIdx.x;
  const int lane16 = t & 15;  // float4 chunk within the 64-ch group
  const int srow = t >> 4;    // 0..31: s-offset within an iteration
  // XCD-swizzled (b,g): bijective over 512 blocks; each XCD (n&7) now sees
  // all 16 g column offsets instead of 2.
  const int n = blockIdx.x;
  const int g = (n >> 3) & 15;
  const int b = ((n >> 7) << 3) | (n & 7);
  const size_t bbase = (size_t)b * SS;  // (b*SS + s) row index
  const int chunk = g * 16 + lane16;    // float4 index within a 256-float4 row

  // ---- Phase A: norms, 4 rows deep. Per-row reduction tree identical to v1.
  for (int it = 0; it < 16; ++it) {
    const int sb = it * 128 + srow;
    float4 v[4];
#pragma unroll
    for (int j = 0; j < 4; ++j) v[j] = x4[(bbase + sb + j * 32) * 256 + chunk];
    double d[4];
#pragma unroll
    for (int j = 0; j < 4; ++j)
      d[j] = (double)v[j].x * v[j].x + (double)v[j].y * v[j].y +
             (double)v[j].z * v[j].z + (double)v[j].w * v[j].w;
#pragma unroll
    for (int m = 1; m <= 8; m <<= 1) {
#pragma unroll
      for (int j = 0; j < 4; ++j) d[j] += shfl_xor_dbl(d[j], m);
    }
    if (lane16 == 0) {
#pragma unroll
      for (int j = 0; j < 4; ++j)
        norm[sb + j * 32] = sqrtf(__fadd_rn((float)d[j], 1e-9f));
    }
  }
  __syncthreads();

  // ---- Phase B: wave 0: bisection for T = K-th largest composite key
  // key = (norm_bits << 11) | (2047 - s); all keys distinct. Lexicographic
  // compare on (norm_bits, s) with ballot+popc counts (bit-exact vs u64).
  if (t < 64) {
    unsigned int nb[32];
#pragma unroll
    for (int j = 0; j < 32; ++j) nb[j] = __float_as_uint(norm[j * 64 + t]);
    unsigned long long T = 0ULL;
    for (int bit = 41; bit >= 0; --bit) {
      const unsigned long long cand = T | (1ULL << bit);
      const unsigned int ch = (unsigned int)(cand >> 11);
      const int scl = 2047 - (int)(cand & 2047ULL);
      int cnt = 0;
#pragma unroll
      for (int j = 0; j < 32; ++j) {
        const bool pred =
            (nb[j] > ch) | ((nb[j] == ch) & ((t + j * 64) <= scl));
        cnt += (int)__popcll(__ballot(pred));
      }
      if (cnt >= KTOP) T = cand;
    }
    if (t == 0) {
      Tch_sh = (unsigned int)(T >> 11);
      Tscl_sh = 2047 - (int)(T & 2047ULL);
    }
  }
  __syncthreads();
  const unsigned int ch = Tch_sh;
  const int scl = Tscl_sh;

  // ---- Phase C: masked passthrough; unselected rows skip the load
  // (selection predicate is uniform per 16-lane group).
  for (int it = 0; it < SS / 32; ++it) {
    const int s = it * 32 + srow;
    const unsigned int nbits = __float_as_uint(norm[s]);
    const bool sel = (nbits > ch) | ((nbits == ch) & (s <= scl));
    float4 v = make_float4(0.f, 0.f, 0.f, 0.f);
    if (sel) v = x4[(bbase + s) * 256 + chunk];
    out4[(bbase + s) * 256 + chunk] = v;
  }
}

extern "C" void kernel_launch(void* const* d_in, const int* in_sizes, int n_in,
                              void* d_out, int out_size, void* d_ws,
                              size_t ws_size, hipStream_t stream) {
  const float4* x4 = (const float4*)d_in[0];
  float4* out4 = (float4*)d_out;
  gsa_v4<<<BB * GG, 512, 0, stream>>>(x4, out4);
}